// Round 14
// baseline (4152.663 us; speedup 1.0000x reference)
//
#include <hip/hip_runtime.h>
#include <hip/hip_fp16.h>
#include <cstdint>
#include <cstddef>

// Sizes: B=64, T=1024, I=64, H=256, G=3H=768, N=B*T=65536

typedef _Float16 f16x8 __attribute__((ext_vector_type(8)));
typedef float f32x4 __attribute__((ext_vector_type(4)));

// Pinned v_dot2_f32_f16 (used by gemm_xw2)
#define DOT2(acc, w, h) \
    asm("v_dot2_f32_f16 %0, %1, %2, %0" : "+v"(acc) : "v"(w), "v"(h))

// Live-range pin per 32-bit word (keeps weight loads hoisted & resident)
#define PIN(x) asm volatile("" : "+v"(x))
#define PIN4(q) do { PIN(q.x); PIN(q.y); PIN(q.z); PIN(q.w); } while (0)

// LDS-only barrier: do NOT drain vmcnt (global loads/stores stay in flight).
__device__ __forceinline__ void lds_barrier() {
    asm volatile("s_waitcnt lgkmcnt(0)\n\ts_barrier" ::: "memory");
}

// Fast transcendentals: raw v_exp (2^x) + v_rcp, no IEEE-div expansion.
__device__ __forceinline__ float fast_sigmoid(float x) {
    float t = x * -1.4426950408889634f, e, r;
    asm("v_exp_f32 %0, %1" : "=v"(e) : "v"(t));
    float d = 1.f + e;
    asm("v_rcp_f32 %0, %1" : "=v"(r) : "v"(d));
    return r;
}
__device__ __forceinline__ float fast_tanh_clamped(float x) {  // |x| <= 15
    float t = x * 2.8853900817779268f, e, r;                   // 2*log2(e)
    asm("v_exp_f32 %0, %1" : "=v"(e) : "v"(t));                // e^(2x)
    float d = e + 1.f;
    asm("v_rcp_f32 %0, %1" : "=v"(r) : "v"(d));
    return 1.f - 2.f * r;
}

// Pack w_hh [768][256] f32 -> [768][256] f16 (row-major halves; stored as half2)
__global__ void pack_whh(const float* __restrict__ w1, const float* __restrict__ w2,
                         __half2* __restrict__ o1, __half2* __restrict__ o2) {
    int g = blockIdx.x;       // 0..767
    int k2 = threadIdx.x;     // 0..127
    const float* w = blockIdx.y ? w2 : w1;
    __half2* o = blockIdx.y ? o2 : o1;
    float a = w[g * 256 + 2 * k2];
    float b = w[g * 256 + 2 * k2 + 1];
    o[g * 128 + k2] = __floats2half2_rn(a, b);
}

// xw1 = x[65536,64] @ w_ih1[768,64]^T + b_ih1 -> f16 [65536,768]
__global__ __launch_bounds__(256)
void gemm_xw1(const float* __restrict__ A, const float* __restrict__ W,
              const float* __restrict__ bias, __half* __restrict__ out) {
    __shared__ float As[64][65];
    __shared__ float Ws[64][65];
    const int tid = threadIdx.x;
    const int n0 = blockIdx.y * 64, g0 = blockIdx.x * 64;
    for (int idx = tid; idx < 4096; idx += 256) {
        int r = idx >> 6, c = idx & 63;
        As[r][c] = A[(size_t)(n0 + r) * 64 + c];
        Ws[r][c] = W[(size_t)(g0 + r) * 64 + c];
    }
    __syncthreads();
    const int ty = tid >> 4, tx = tid & 15;
    float acc[4][4] = {};
    for (int k = 0; k < 64; ++k) {
        float a[4], w[4];
        #pragma unroll
        for (int i = 0; i < 4; ++i) a[i] = As[ty * 4 + i][k];
        #pragma unroll
        for (int jj = 0; jj < 4; ++jj) w[jj] = Ws[tx * 4 + jj][k];
        #pragma unroll
        for (int i = 0; i < 4; ++i)
            #pragma unroll
            for (int jj = 0; jj < 4; ++jj) acc[i][jj] += a[i] * w[jj];
    }
    #pragma unroll
    for (int jj = 0; jj < 4; ++jj) {
        float bb = bias[g0 + tx * 4 + jj];
        #pragma unroll
        for (int i = 0; i < 4; ++i)
            out[(size_t)(n0 + ty * 4 + i) * 768 + (g0 + tx * 4 + jj)] =
                __float2half(acc[i][jj] + bb);
    }
}

// xw2 = y1[65536,256](f16) @ w_eff[768,256](f16)^T + b_eff -> f16 [65536,768]
__global__ __launch_bounds__(256)
void gemm_xw2(const __half2* __restrict__ A, const __half2* __restrict__ W,
              const float* __restrict__ bias, __half* __restrict__ out) {
    __shared__ __half2 As[64][33];
    __shared__ __half2 Ws[64][33];
    const int tid = threadIdx.x;
    const int n0 = blockIdx.y * 64, g0 = blockIdx.x * 64;
    const int ty = tid >> 4, tx = tid & 15;
    float acc[4][4] = {};
    for (int kc = 0; kc < 4; ++kc) {
        __syncthreads();
        for (int idx = tid; idx < 2048; idx += 256) {
            int r = idx >> 5, c2 = idx & 31;
            As[r][c2] = A[(size_t)(n0 + r) * 128 + kc * 32 + c2];
            Ws[r][c2] = W[(size_t)(g0 + r) * 128 + kc * 32 + c2];
        }
        __syncthreads();
        #pragma unroll 8
        for (int k2 = 0; k2 < 32; ++k2) {
            unsigned int a2[4], w2[4];
            #pragma unroll
            for (int i = 0; i < 4; ++i)
                a2[i] = __builtin_bit_cast(unsigned int, As[ty * 4 + i][k2]);
            #pragma unroll
            for (int jj = 0; jj < 4; ++jj)
                w2[jj] = __builtin_bit_cast(unsigned int, Ws[tx * 4 + jj][k2]);
            #pragma unroll
            for (int i = 0; i < 4; ++i)
                #pragma unroll
                for (int jj = 0; jj < 4; ++jj)
                    DOT2(acc[i][jj], w2[jj], a2[i]);
        }
    }
    #pragma unroll
    for (int jj = 0; jj < 4; ++jj) {
        float bb = bias[g0 + tx * 4 + jj];
        #pragma unroll
        for (int i = 0; i < 4; ++i)
            out[(size_t)(n0 + ty * 4 + i) * 768 + (g0 + tx * 4 + jj)] =
                __float2half(acc[i][jj] + bb);
    }
}

// GRU recurrence on the MATRIX pipe. 64 blocks x 1 batch; 512 threads = 8 waves.
// Wave w owns units [w*32, w*32+32) = gate rows {u, 256+u, 512+u}.
// Weights live as 48 MFMA B-fragments (192 regs/thread, AGPR-native, no copy
// tax -- v_dot2 on the VALU was measured ~half-rate and was the bottleneck).
// h is row 0 of a 16x16x32 MFMA A-tile (rows 1-15 zero); per step, per wave:
// 2 passes x (8 ds_read_b128 A-frags + 24 MFMA), then lanes 0-15 run the gate
// nonlinearity (raw v_exp/v_rcp) for 2 units each.
// MFMA A-frag: lane l elem j = A[l&15][(l>>4)*8+j]; B-frag: B[(l>>4)*8+j][l&15];
// D reg i = D[(l>>4)*4+i][l&15]  (gfx950-verified C/D layout; A/B standard).
template<int LAYER>
__global__ __launch_bounds__(512, 2)
void rec_kernel(const __half2* __restrict__ wpack,  // [768][256] f16 row-major
                const float* __restrict__ b_hh,     // [768]
                const __half* __restrict__ xw,      // [64][1024][768]
                __half* __restrict__ y_out,         // LAYER==1: [64][1024][256]
                float* __restrict__ stats,          // sum[256], sumsq[256]
                float* __restrict__ mx_out,         // LAYER==2: [64][256]
                float* __restrict__ mn_out) {
    __shared__ __align__(16) __half hb[2][16][264];  // 16.9KB, rows 1-15 stay 0
    const int tid = threadIdx.x;
    const int w = tid >> 6, l = tid & 63;
    const int lm = l & 15, lk = l >> 4;
    const int b = blockIdx.x;

    // B-fragments: [sel][gate][kt]; row = g*256 + w*32 + sel*16 + lm,
    // k = kt*32 + lk*8 .. +8  (16B contiguous in the row-major packed weights)
    uint4 Bf[2][3][8];
    {
        const char* wbase = (const char*)wpack;
        #pragma unroll
        for (int sel = 0; sel < 2; ++sel)
            #pragma unroll
            for (int g = 0; g < 3; ++g)
                #pragma unroll
                for (int kt = 0; kt < 8; ++kt) {
                    int gr = g * 256 + w * 32 + sel * 16 + lm;
                    Bf[sel][g][kt] =
                        *(const uint4*)(wbase + (size_t)gr * 512 + kt * 64 + lk * 16);
                    PIN4(Bf[sel][g][kt]);
                }
    }

    const int u0 = w * 32 + lm, u1 = u0 + 16;
    const float br0 = b_hh[u0], bz0 = b_hh[256 + u0], bn0 = b_hh[512 + u0];
    const float br1 = b_hh[u1], bz1 = b_hh[256 + u1], bn1 = b_hh[512 + u1];

    // zero both h buffers (rows 1-15 are never written again)
    for (int idx = tid; idx < 1056; idx += 512) ((uint4*)hb)[idx] = uint4{0u,0u,0u,0u};

    float hp0 = 0.f, hp1 = 0.f;
    float ssum0 = 0.f, ssq0 = 0.f, ssum1 = 0.f, ssq1 = 0.f;
    float mx0 = -3e38f, mn0 = 3e38f, mx1 = -3e38f, mn1 = 3e38f;
    const __half* xwp = xw + (size_t)b * 1024 * 768;
    __half* yp = y_out + (size_t)b * 1024 * 256;

    // prefetch t=0 xw (all lanes load valid addrs; only lanes<16 consume)
    __half nxr0 = xwp[u0], nxz0 = xwp[256 + u0], nxn0 = xwp[512 + u0];
    __half nxr1 = xwp[u1], nxz1 = xwp[256 + u1], nxn1 = xwp[512 + u1];
    __syncthreads();

    const char* hb_base = (const char*)hb;

    for (int t = 0; t < 1024; ++t) {
        __half cxr0 = nxr0, cxz0 = nxz0, cxn0 = nxn0;
        __half cxr1 = nxr1, cxz1 = nxz1, cxn1 = nxn1;
        // prefetch t+1 (t=1023 over-read lands in adjacent ws region; discarded)
        const __half* xq = xwp + (size_t)(t + 1) * 768;
        nxr0 = xq[u0]; nxz0 = xq[256 + u0]; nxn0 = xq[512 + u0];
        nxr1 = xq[u1]; nxz1 = xq[256 + u1]; nxn1 = xq[512 + u1];

        const size_t abase = (size_t)(t & 1) * 8448 + (size_t)lm * 528 + lk * 16;
        __half* hwr = &hb[(t + 1) & 1][0][0];

        #pragma unroll
        for (int sel = 0; sel < 2; ++sel) {
            f32x4 ar = {0.f, 0.f, 0.f, 0.f};
            f32x4 az = {0.f, 0.f, 0.f, 0.f};
            f32x4 an = {0.f, 0.f, 0.f, 0.f};
            #pragma unroll
            for (int kt = 0; kt < 8; ++kt) {
                f16x8 a = *(const f16x8*)(hb_base + abase + kt * 64);
                ar = __builtin_amdgcn_mfma_f32_16x16x32_f16(
                        a, __builtin_bit_cast(f16x8, Bf[sel][0][kt]), ar, 0, 0, 0);
                az = __builtin_amdgcn_mfma_f32_16x16x32_f16(
                        a, __builtin_bit_cast(f16x8, Bf[sel][1][kt]), az, 0, 0, 0);
                an = __builtin_amdgcn_mfma_f32_16x16x32_f16(
                        a, __builtin_bit_cast(f16x8, Bf[sel][2][kt]), an, 0, 0, 0);
            }
            if (l < 16) {
                float xr = __half2float(sel ? cxr1 : cxr0);
                float xz = __half2float(sel ? cxz1 : cxz0);
                float xn = __half2float(sel ? cxn1 : cxn0);
                float hr = ar[0] + (sel ? br1 : br0);
                float hz = az[0] + (sel ? bz1 : bz0);
                float hn = an[0] + (sel ? bn1 : bn0);
                float r = fast_sigmoid(xr + hr);
                float z = fast_sigmoid(xz + hz);
                float pa = xn + r * hn;
                pa = fminf(fmaxf(pa, -15.f), 15.f);
                float nn = fast_tanh_clamped(pa);
                float hprev = sel ? hp1 : hp0;
                float h = (1.f - z) * nn + z * hprev;
                int u = sel ? u1 : u0;
                if (sel) {
                    hp1 = h; ssum1 += h; ssq1 += h * h;
                    if (LAYER == 2) { mx1 = fmaxf(mx1, h); mn1 = fminf(mn1, h); }
                } else {
                    hp0 = h; ssum0 += h; ssq0 += h * h;
                    if (LAYER == 2) { mx0 = fmaxf(mx0, h); mn0 = fminf(mn0, h); }
                }
                __half yh = __float2half(h);
                hwr[u] = yh;                                   // row 0 of next buf
                if (LAYER == 1) yp[(size_t)t * 256 + u] = yh;  // stays in flight
            }
        }
        lds_barrier();   // LDS-only drain: xw loads / y stores not drained
    }
    if (l < 16) {
        atomicAdd(&stats[u0], ssum0);
        atomicAdd(&stats[256 + u0], ssq0);
        atomicAdd(&stats[u1], ssum1);
        atomicAdd(&stats[256 + u1], ssq1);
        if (LAYER == 2) {
            mx_out[b * 256 + u0] = mx0;
            mn_out[b * 256 + u0] = mn0;
            mx_out[b * 256 + u1] = mx1;
            mn_out[b * 256 + u1] = mn1;
        }
    }
}

// Fold BN1 (training-mode batch stats) into layer-2 input weights.
__global__ void fold_bn1(const float* __restrict__ w_ih2, const float* __restrict__ b_ih2,
                         const float* __restrict__ g1, const float* __restrict__ be1,
                         const float* __restrict__ stats1,
                         __half* __restrict__ w_eff, float* __restrict__ b_eff) {
    const int g = blockIdx.x, lane = threadIdx.x;  // 768 blocks x 64 threads
    const float invN = 1.f / 65536.f;
    float partial = 0.f;
    for (int c = lane; c < 256; c += 64) {
        float mu = stats1[c] * invN;
        float var = stats1[256 + c] * invN - mu * mu;
        float s = g1[c] * rsqrtf(var + 1e-5f);
        float sh = be1[c] - mu * s;
        float w = w_ih2[g * 256 + c];
        w_eff[g * 256 + c] = __float2half(w * s);
        partial += w * sh;
    }
    #pragma unroll
    for (int off = 32; off > 0; off >>= 1) partial += __shfl_down(partial, off);
    if (lane == 0) b_eff[g] = b_ih2[g] + partial;
}

// BN2 affine -> time max-pool (max if scale>=0 else min) -> tanh -> FC
__global__ void final_kernel(const float* __restrict__ stats2,
                             const float* __restrict__ mx, const float* __restrict__ mn,
                             const float* __restrict__ g2, const float* __restrict__ be2,
                             const float* __restrict__ w_fc, const float* __restrict__ b_fc,
                             float* __restrict__ out) {
    __shared__ float v[256];
    const int b = blockIdx.x, c = threadIdx.x;
    const float invN = 1.f / 65536.f;
    float mu = stats2[c] * invN;
    float var = stats2[256 + c] * invN - mu * mu;
    float s = g2[c] * rsqrtf(var + 1e-5f);
    float d = be2[c] - mu * s;
    float M = (s >= 0.f) ? mx[b * 256 + c] : mn[b * 256 + c];
    v[c] = tanhf(s * M + d);
    __syncthreads();
    if (c < 128) {
        float acc = b_fc[c];
        for (int k = 0; k < 256; ++k) acc += v[k] * w_fc[c * 256 + k];
        out[b * 128 + c] = acc;
    }
}

extern "C" void kernel_launch(void* const* d_in, const int* in_sizes, int n_in,
                              void* d_out, int out_size, void* d_ws, size_t ws_size,
                              hipStream_t stream) {
    const float* x     = (const float*)d_in[0];
    const float* w_ih1 = (const float*)d_in[1];
    const float* w_hh1 = (const float*)d_in[2];
    const float* b_ih1 = (const float*)d_in[3];
    const float* b_hh1 = (const float*)d_in[4];
    const float* g1    = (const float*)d_in[5];
    const float* be1   = (const float*)d_in[6];
    const float* w_ih2 = (const float*)d_in[7];
    const float* w_hh2 = (const float*)d_in[8];
    const float* b_ih2 = (const float*)d_in[9];
    const float* b_hh2 = (const float*)d_in[10];
    const float* g2    = (const float*)d_in[11];
    const float* be2   = (const float*)d_in[12];
    const float* w_fc  = (const float*)d_in[13];
    const float* b_fc  = (const float*)d_in[14];
    float* out = (float*)d_out;

    char* ws = (char*)d_ws;
    size_t off = 0;
    __half*  xw   = (__half*)(ws + off);  off += (size_t)65536 * 768 * 2;  // shared by both layers
    __half*  y1   = (__half*)(ws + off);  off += (size_t)65536 * 256 * 2;
    __half2* wp1  = (__half2*)(ws + off); off += (size_t)768 * 128 * 4;
    __half2* wp2  = (__half2*)(ws + off); off += (size_t)768 * 128 * 4;
    __half*  weff = (__half*)(ws + off);  off += (size_t)768 * 256 * 2;
    float*   beff = (float*)(ws + off);   off += (size_t)768 * 4;
    float*   stats= (float*)(ws + off);   off += (size_t)1024 * 4;         // sum1,sq1,sum2,sq2
    float*   mx2  = (float*)(ws + off);   off += (size_t)64 * 256 * 4;
    float*   mn2  = (float*)(ws + off);   off += (size_t)64 * 256 * 4;

    (void)hipMemsetAsync(stats, 0, 4096, stream);

    pack_whh<<<dim3(768, 2), dim3(128), 0, stream>>>(w_hh1, w_hh2, wp1, wp2);
    gemm_xw1<<<dim3(12, 1024), dim3(256), 0, stream>>>(x, w_ih1, b_ih1, xw);
    rec_kernel<1><<<dim3(64), dim3(512), 0, stream>>>(wp1, b_hh1, xw, y1, stats,
                                                      (float*)nullptr, (float*)nullptr);
    fold_bn1<<<dim3(768), dim3(64), 0, stream>>>(w_ih2, b_ih2, g1, be1, stats, weff, beff);
    gemm_xw2<<<dim3(12, 1024), dim3(256), 0, stream>>>((const __half2*)y1, (const __half2*)weff,
                                                       beff, xw);
    rec_kernel<2><<<dim3(64), dim3(512), 0, stream>>>(wp2, b_hh2, xw, y1,
                                                      stats + 512, mx2, mn2);
    final_kernel<<<dim3(64), dim3(256), 0, stream>>>(stats + 512, mx2, mn2, g2, be2,
                                                     w_fc, b_fc, out);
}